// Round 2
// baseline (594.584 us; speedup 1.0000x reference)
//
#include <hip/hip_runtime.h>
#include <hip/hip_bf16.h>

#define B_SZ   16384
#define IN_DIM 4096
#define H1D    128
#define H2D    64
#define LAT    32

typedef _Float16 half8 __attribute__((ext_vector_type(8)));
typedef _Float16 half4 __attribute__((ext_vector_type(4)));
typedef float float4v __attribute__((ext_vector_type(4)));

// ---- workspace layout (bytes) ----
#define WS_W2T  1048576
#define WS_W3T  1064960
#define WS_WDT  1069056
#define WS_B3O  1331200

// -------- prepass: transpose + fp32->fp16 convert weights, fold qparams into b3 --------
__global__ __launch_bounds__(256) void prep_kernel(
    const float* __restrict__ W1, const float* __restrict__ W2,
    const float* __restrict__ W3, const float* __restrict__ Wd,
    const float* __restrict__ b3, const float* __restrict__ qp,
    _Float16* __restrict__ W1t, _Float16* __restrict__ W2t,
    _Float16* __restrict__ W3t, _Float16* __restrict__ Wdt,
    float* __restrict__ b3off)
{
    int t = blockIdx.x * 256 + threadIdx.x;
    if (t < IN_DIM * H1D) {              // W1[k][n] -> W1t[n][k]
        int k = t >> 7, n = t & 127;
        W1t[n * IN_DIM + k] = (_Float16)W1[t];
    }
    if (t < LAT * IN_DIM) {              // Wd[k][n] -> Wdt[n][k]
        int k = t >> 12, n = t & 4095;
        Wdt[n * LAT + k] = (_Float16)Wd[t];
    }
    if (t < H1D * H2D) {                 // W2[k][n] -> W2t[n][k]
        int k = t >> 6, n = t & 63;
        W2t[n * H1D + k] = (_Float16)W2[t];
    }
    if (t < H2D * LAT) {                 // W3[k][n] -> W3t[n][k]
        int k = t >> 5, n = t & 31;
        W3t[n * H2D + k] = (_Float16)W3[t];
    }
    if (t < LAT) {
        float s = b3[t];
        #pragma unroll
        for (int r = 0; r < 6; ++r) s += qp[r * LAT + t];
        b3off[t] = s;
    }
}

static __device__ __forceinline__ half8 cvt8(float4v v0, float4v v1) {
    half8 h;
    h[0] = (_Float16)v0[0]; h[1] = (_Float16)v0[1];
    h[2] = (_Float16)v0[2]; h[3] = (_Float16)v0[3];
    h[4] = (_Float16)v1[0]; h[5] = (_Float16)v1[1];
    h[6] = (_Float16)v1[2]; h[7] = (_Float16)v1[3];
    return h;
}

// -------- fused kernel: full forward for 16 rows per block --------
// 1024 blocks x 256 threads, 4 blocks/CU resident (38.1 KB LDS, VGPR<=128).
// Round-1 post-mortem: 512 blocks x 76 KB LDS = 2 blocks/CU = 2 waves/SIMD ->
// latency-bound (MfmaUtil 3.8%, HBM 31%, Occ 19.7%). Halving rows/block and
// the K-split partial buffer doubles grid AND doubles blocks/CU -> 16 waves/CU.
__global__ __launch_bounds__(256, 4) void fused_kernel(
    const float* __restrict__ x,
    const _Float16* __restrict__ W1t, const _Float16* __restrict__ W2t,
    const _Float16* __restrict__ W3t, const _Float16* __restrict__ Wdt,
    const float* __restrict__ b1, const float* __restrict__ b2,
    const float* __restrict__ b3off, const float* __restrict__ bd,
    float* __restrict__ out)
{
    __shared__ alignas(16) float part[4 * 16 * 132];   // 33792 B, K-split partials
    __shared__ alignas(16) _Float16 h1s[16 * 136];     // 4352 B
    _Float16* h2s = (_Float16*)part;                   // [16][72], aliases part (dead by then)
    _Float16* qs  = h1s;                               // [16][40], aliases h1s (dead by then)

    const int tid  = threadIdx.x;
    const int lane = tid & 63;
    const int w    = tid >> 6;        // 0..3  = K-quarter / col-quarter
    const int l15  = lane & 15;
    const int quad = lane >> 4;       // 0..3
    const int rb0  = blockIdx.x * 16;

    // ---- phase A: layer 1, acc[8 col-frags], K-chunk = 1024 per wave ----
    float4v acc[8];
    #pragma unroll
    for (int ct = 0; ct < 8; ++ct)
        acc[ct] = (float4v){0.f, 0.f, 0.f, 0.f};

    const float* xp0 = x + (size_t)(rb0 + l15) * IN_DIM + w * 1024 + quad * 8;
    const _Float16* wp[8];
    #pragma unroll
    for (int ct = 0; ct < 8; ++ct)
        wp[ct] = W1t + (size_t)(ct * 16 + l15) * IN_DIM + w * 1024 + quad * 8;

    #pragma unroll 2
    for (int kk = 0; kk < 32; ++kk) {
        const int ko = kk * 32;
        // non-temporal: x is streamed exactly once; keep weights resident in L2
        float4v x00 = __builtin_nontemporal_load((const float4v*)(xp0 + ko));
        float4v x01 = __builtin_nontemporal_load((const float4v*)(xp0 + ko + 4));
        half8 a0 = cvt8(x00, x01);
        #pragma unroll
        for (int ct = 0; ct < 8; ++ct) {
            half8 b = *(const half8*)(wp[ct] + ko);
            acc[ct] = __builtin_amdgcn_mfma_f32_16x16x32_f16(a0, b, acc[ct], 0, 0, 0);
        }
    }

    // write per-wave partials to LDS
    {
        float* pw = part + w * (16 * 132);
        #pragma unroll
        for (int ct = 0; ct < 8; ++ct)
            #pragma unroll
            for (int r = 0; r < 4; ++r)
                pw[(quad * 4 + r) * 132 + ct * 16 + l15] = acc[ct][r];
    }
    __syncthreads();

    // reduce 4 partials + bias + relu -> h1s fp16 [16][136]
    #pragma unroll
    for (int i = 0; i < 2; ++i) {
        int chunk = tid * 2 + i;          // 0..511 float4 chunks of [16][128]
        int row = chunk >> 5;
        int c4  = chunk & 31;
        const float* p = part + row * 132 + c4 * 4;
        float4v s = *(const float4v*)(p)
                  + *(const float4v*)(p + 16 * 132)
                  + *(const float4v*)(p + 2 * 16 * 132)
                  + *(const float4v*)(p + 3 * 16 * 132);
        float4v bb = *(const float4v*)(b1 + c4 * 4);
        s = s + bb;
        half4 h;
        h[0] = (_Float16)(s[0] > 0.f ? s[0] : 0.f);
        h[1] = (_Float16)(s[1] > 0.f ? s[1] : 0.f);
        h[2] = (_Float16)(s[2] > 0.f ? s[2] : 0.f);
        h[3] = (_Float16)(s[3] > 0.f ? s[3] : 0.f);
        *(half4*)(h1s + row * 136 + c4 * 4) = h;
    }
    __syncthreads();

    // ---- phase B: layer 2: h2[16][64] = relu(h1 @ W2 + b2); wave w -> cols w*16..+15 ----
    {
        float bv2 = b2[w * 16 + l15];
        float4v a2 = (float4v){bv2, bv2, bv2, bv2};
        #pragma unroll
        for (int kk = 0; kk < 4; ++kk) {
            half8 b = *(const half8*)(W2t + (w * 16 + l15) * H1D + kk * 32 + quad * 8);
            half8 a0 = *(const half8*)(h1s + l15 * 136 + kk * 32 + quad * 8);
            a2 = __builtin_amdgcn_mfma_f32_16x16x32_f16(a0, b, a2, 0, 0, 0);
        }
        // part-reads all completed before the previous barrier; h2s (alias) safe
        #pragma unroll
        for (int r = 0; r < 4; ++r) {
            float v = a2[r];
            h2s[(quad * 4 + r) * 72 + w * 16 + l15] = (_Float16)(v > 0.f ? v : 0.f);
        }
    }
    __syncthreads();

    // ---- layer 3 + cos -> qs[16][40] fp16 in LDS; waves 0,1 -> col halves ----
    if (w < 2) {
        const int c3 = w * 16 + l15;
        float bv3 = b3off[c3];
        float4v a3 = (float4v){bv3, bv3, bv3, bv3};
        #pragma unroll
        for (int kk = 0; kk < 2; ++kk) {
            half8 a = *(const half8*)(h2s + l15 * 72 + kk * 32 + quad * 8);
            half8 b = *(const half8*)(W3t + c3 * H2D + kk * 32 + quad * 8);
            a3 = __builtin_amdgcn_mfma_f32_16x16x32_f16(a, b, a3, 0, 0, 0);
        }
        #pragma unroll
        for (int r = 0; r < 4; ++r)
            qs[(quad * 4 + r) * 40 + c3] = (_Float16)cosf(a3[r]);
    }
    __syncthreads();

    // ---- phase C: decode out[16][4096] = q @ Wd + bd; wave w -> cols [w*1024, +1024) ----
    // Swapped operands: A-frag = Wd^T rows (output cols), B-frag = q rows (output rows).
    // D layout: reg axis (quad*4+r) = output COLUMN -> each lane's 4 regs are 4
    // consecutive floats of one output row => dwordx4 store, 16 rows x 64 B / instr.
    // Plain (cached) stores: round-1 NT stores showed WRITE_SIZE 360 MB vs 268 ideal
    // (64 B-granular write-through); let L2 combine to full lines.
    {
        const int wbase = w * 1024;
        half8 bq = *(const half8*)(qs + l15 * 40 + quad * 8);   // q rows 0..15
        const _Float16* wdp = Wdt + (size_t)(wbase + l15) * LAT + quad * 8;
        const float* bdp = bd + wbase + quad * 4;
        float* op0 = out + (size_t)(rb0 + l15) * IN_DIM + wbase + quad * 4;
        #pragma unroll 4
        for (int ct = 0; ct < 64; ++ct) {
            half8 aw = *(const half8*)(wdp + ct * 16 * LAT);
            float4v bias = *(const float4v*)(bdp + ct * 16);
            float4v o0 = __builtin_amdgcn_mfma_f32_16x16x32_f16(aw, bq, bias, 0, 0, 0);
            *(float4v*)(op0 + ct * 16) = o0;
        }
    }
}

extern "C" void kernel_launch(void* const* d_in, const int* in_sizes, int n_in,
                              void* d_out, int out_size, void* d_ws, size_t ws_size,
                              hipStream_t stream)
{
    const float* x  = (const float*)d_in[0];
    const float* W1 = (const float*)d_in[1];
    const float* b1 = (const float*)d_in[2];
    const float* W2 = (const float*)d_in[3];
    const float* b2 = (const float*)d_in[4];
    const float* W3 = (const float*)d_in[5];
    const float* b3 = (const float*)d_in[6];
    const float* qp = (const float*)d_in[7];
    const float* Wd = (const float*)d_in[8];
    const float* bd = (const float*)d_in[9];
    float* out = (float*)d_out;

    char* ws = (char*)d_ws;
    _Float16* W1t = (_Float16*)(ws);
    _Float16* W2t = (_Float16*)(ws + WS_W2T);
    _Float16* W3t = (_Float16*)(ws + WS_W3T);
    _Float16* Wdt = (_Float16*)(ws + WS_WDT);
    float*    b3o = (float*)(ws + WS_B3O);

    prep_kernel<<<2048, 256, 0, stream>>>(W1, W2, W3, Wd, b3, qp, W1t, W2t, W3t, Wdt, b3o);
    fused_kernel<<<1024, 256, 0, stream>>>(x, W1t, W2t, W3t, Wdt, b1, b2, b3o, bd, out);
}

// Round 3
// 527.740 us; speedup vs baseline: 1.1267x; 1.1267x over previous
//
#include <hip/hip_runtime.h>
#include <hip/hip_bf16.h>

#define B_SZ   16384
#define IN_DIM 4096
#define H1D    128
#define H2D    64
#define LAT    32

typedef _Float16 half8 __attribute__((ext_vector_type(8)));
typedef _Float16 half4 __attribute__((ext_vector_type(4)));
typedef float float4v __attribute__((ext_vector_type(4)));

// ---- workspace layout (bytes) ----
#define WS_W2T  1048576
#define WS_W3T  1064960
#define WS_WDT  1069056
#define WS_B3O  1331200
#define WS_Q    1331328

// -------- prepass: transpose + fp32->fp16 convert weights, fold qparams into b3 --------
__global__ __launch_bounds__(256) void prep_kernel(
    const float* __restrict__ W1, const float* __restrict__ W2,
    const float* __restrict__ W3, const float* __restrict__ Wd,
    const float* __restrict__ b3, const float* __restrict__ qp,
    _Float16* __restrict__ W1t, _Float16* __restrict__ W2t,
    _Float16* __restrict__ W3t, _Float16* __restrict__ Wdt,
    float* __restrict__ b3off)
{
    int t = blockIdx.x * 256 + threadIdx.x;
    if (t < IN_DIM * H1D) {              // W1[k][n] -> W1t[n][k]
        int k = t >> 7, n = t & 127;
        W1t[n * IN_DIM + k] = (_Float16)W1[t];
    }
    if (t < LAT * IN_DIM) {              // Wd[k][n] -> Wdt[n][k]
        int k = t >> 12, n = t & 4095;
        Wdt[n * LAT + k] = (_Float16)Wd[t];
    }
    if (t < H1D * H2D) {                 // W2[k][n] -> W2t[n][k]
        int k = t >> 6, n = t & 63;
        W2t[n * H1D + k] = (_Float16)W2[t];
    }
    if (t < H2D * LAT) {                 // W3[k][n] -> W3t[n][k]
        int k = t >> 5, n = t & 31;
        W3t[n * H2D + k] = (_Float16)W3[t];
    }
    if (t < LAT) {
        float s = b3[t];
        #pragma unroll
        for (int r = 0; r < 6; ++r) s += qp[r * LAT + t];
        b3off[t] = s;
    }
}

static __device__ __forceinline__ half8 cvt8(float4v v0, float4v v1) {
    half8 h;
    h[0] = (_Float16)v0[0]; h[1] = (_Float16)v0[1];
    h[2] = (_Float16)v0[2]; h[3] = (_Float16)v0[3];
    h[4] = (_Float16)v1[0]; h[5] = (_Float16)v1[1];
    h[6] = (_Float16)v1[2]; h[7] = (_Float16)v1[3];
    return h;
}

// -------- encoder: barrier-free K-loop, K-split across 4 waves (round-0 verbatim) --------
// 512 blocks x 256 threads; block = 32 rows of x; wave w owns K-quarter [w*1024, w*1024+1024)
__global__ __launch_bounds__(256, 2) void encoder_kernel(
    const float* __restrict__ x,
    const _Float16* __restrict__ W1t, const _Float16* __restrict__ W2t,
    const _Float16* __restrict__ W3t,
    const float* __restrict__ b1, const float* __restrict__ b2,
    const float* __restrict__ b3off, _Float16* __restrict__ qout)
{
    __shared__ alignas(16) float part[4 * 32 * 132];   // 67584 B, K-split partials
    __shared__ alignas(16) _Float16 h1s[32 * 136];     // 8704 B
    _Float16* h2s = (_Float16*)part;                   // [32][72], aliases part (dead by then)

    const int tid  = threadIdx.x;
    const int lane = tid & 63;
    const int w    = tid >> 6;        // 0..3  = K-quarter
    const int l15  = lane & 15;
    const int quad = lane >> 4;       // 0..3
    const int rb0  = blockIdx.x * 32;

    // ---- layer 1: acc[2 row-frags][8 col-frags], K-chunk = 1024 per wave ----
    float4v acc[2][8];
    #pragma unroll
    for (int mg = 0; mg < 2; ++mg)
        #pragma unroll
        for (int ct = 0; ct < 8; ++ct)
            acc[mg][ct] = (float4v){0.f, 0.f, 0.f, 0.f};

    const float* xp0 = x + (size_t)(rb0 + l15) * IN_DIM + w * 1024 + quad * 8;
    const float* xp1 = xp0 + 16 * IN_DIM;
    const _Float16* wp[8];
    #pragma unroll
    for (int ct = 0; ct < 8; ++ct)
        wp[ct] = W1t + (size_t)(ct * 16 + l15) * IN_DIM + w * 1024 + quad * 8;

    #pragma unroll 2
    for (int kk = 0; kk < 32; ++kk) {
        const int ko = kk * 32;
        float4v x00 = *(const float4v*)(xp0 + ko);
        float4v x01 = *(const float4v*)(xp0 + ko + 4);
        float4v x10 = *(const float4v*)(xp1 + ko);
        float4v x11 = *(const float4v*)(xp1 + ko + 4);
        half8 a0 = cvt8(x00, x01);
        half8 a1 = cvt8(x10, x11);
        #pragma unroll
        for (int ct = 0; ct < 8; ++ct) {
            half8 b = *(const half8*)(wp[ct] + ko);
            acc[0][ct] = __builtin_amdgcn_mfma_f32_16x16x32_f16(a0, b, acc[0][ct], 0, 0, 0);
            acc[1][ct] = __builtin_amdgcn_mfma_f32_16x16x32_f16(a1, b, acc[1][ct], 0, 0, 0);
        }
    }

    // write per-wave partials to LDS
    {
        float* pw = part + w * (32 * 132);
        #pragma unroll
        for (int mg = 0; mg < 2; ++mg)
            #pragma unroll
            for (int ct = 0; ct < 8; ++ct)
                #pragma unroll
                for (int r = 0; r < 4; ++r)
                    pw[(mg * 16 + quad * 4 + r) * 132 + ct * 16 + l15] = acc[mg][ct][r];
    }
    __syncthreads();

    // reduce 4 partials + bias + relu -> h1s fp16 [32][136]
    #pragma unroll
    for (int i = 0; i < 4; ++i) {
        int chunk = tid * 4 + i;          // 0..1023 float4 chunks of [32][128]
        int row = chunk >> 5;
        int c4  = chunk & 31;
        const float* p = part + row * 132 + c4 * 4;
        float4v s = *(const float4v*)(p)
                  + *(const float4v*)(p + 32 * 132)
                  + *(const float4v*)(p + 2 * 32 * 132)
                  + *(const float4v*)(p + 3 * 32 * 132);
        float4v bb = *(const float4v*)(b1 + c4 * 4);
        s = s + bb;
        half4 h;
        h[0] = (_Float16)(s[0] > 0.f ? s[0] : 0.f);
        h[1] = (_Float16)(s[1] > 0.f ? s[1] : 0.f);
        h[2] = (_Float16)(s[2] > 0.f ? s[2] : 0.f);
        h[3] = (_Float16)(s[3] > 0.f ? s[3] : 0.f);
        *(half4*)(h1s + row * 136 + c4 * 4) = h;
    }
    __syncthreads();

    // ---- layer 2: h2[32][64] = relu(h1 @ W2 + b2); wave w -> cols w*16..+15 ----
    {
        float bv2 = b2[w * 16 + l15];
        float4v a2[2] = {(float4v){bv2, bv2, bv2, bv2}, (float4v){bv2, bv2, bv2, bv2}};
        #pragma unroll
        for (int kk = 0; kk < 4; ++kk) {
            half8 b = *(const half8*)(W2t + (w * 16 + l15) * H1D + kk * 32 + quad * 8);
            half8 a0 = *(const half8*)(h1s + l15 * 136 + kk * 32 + quad * 8);
            half8 a1 = *(const half8*)(h1s + (16 + l15) * 136 + kk * 32 + quad * 8);
            a2[0] = __builtin_amdgcn_mfma_f32_16x16x32_f16(a0, b, a2[0], 0, 0, 0);
            a2[1] = __builtin_amdgcn_mfma_f32_16x16x32_f16(a1, b, a2[1], 0, 0, 0);
        }
        __syncthreads();   // h2s aliases part; ensure reduction reads are done
        #pragma unroll
        for (int mg = 0; mg < 2; ++mg)
            #pragma unroll
            for (int r = 0; r < 4; ++r) {
                float v = a2[mg][r];
                h2s[(mg * 16 + quad * 4 + r) * 72 + w * 16 + l15] = (_Float16)(v > 0.f ? v : 0.f);
            }
    }
    __syncthreads();

    // ---- layer 3 + cos: wave w -> row-group w>>1, col-group w&1 ----
    {
        const int mg3 = w >> 1;
        const int ct3 = w & 1;
        const int c3  = ct3 * 16 + l15;
        float bv3 = b3off[c3];
        float4v a3 = (float4v){bv3, bv3, bv3, bv3};
        #pragma unroll
        for (int kk = 0; kk < 2; ++kk) {
            half8 a = *(const half8*)(h2s + (mg3 * 16 + l15) * 72 + kk * 32 + quad * 8);
            half8 b = *(const half8*)(W3t + c3 * H2D + kk * 32 + quad * 8);
            a3 = __builtin_amdgcn_mfma_f32_16x16x32_f16(a, b, a3, 0, 0, 0);
        }
        #pragma unroll
        for (int r = 0; r < 4; ++r) {
            int row = rb0 + mg3 * 16 + quad * 4 + r;
            qout[(size_t)row * LAT + c3] = (_Float16)cosf(a3[r]);
        }
    }
}

// -------- decoder: out[16384,4096] = q @ Wd + bd --------
// Swapped-operand MFMA (A = Wd^T rows = output cols, B = q rows): D-fragment reg
// axis (quad*4+r) runs along output COLUMNS -> each lane stores 4 consecutive
// floats of one output row via global_store_dwordx4. No LDS, no barriers.
// q tile for 16 rows is 1 KB *contiguous* in global -> one half8 load per lane.
// 4096 blocks x 256 threads (16 rows x 1024 cols per block, wave w -> 256 cols).
__global__ __launch_bounds__(256, 8) void decoder_kernel(
    const _Float16* __restrict__ qin, const _Float16* __restrict__ Wdt,
    const float* __restrict__ bd, float* __restrict__ out)
{
    const int tid  = threadIdx.x;
    const int lane = tid & 63;
    const int w    = tid >> 6;        // 0..3
    const int l15  = lane & 15;
    const int quad = lane >> 4;       // 0..3
    const int stripe   = blockIdx.x >> 2;   // 0..1023 -> 16 rows each
    const int colchunk = blockIdx.x & 3;    // 0..3    -> 1024 cols each
    const int rb    = stripe * 16;
    const int cbase = colchunk * 1024 + w * 256;

    // q fragment: rows rb..rb+15, B-operand (row l15, k = quad*8..+8)
    half8 bq = *(const half8*)(qin + (size_t)(rb + l15) * LAT + quad * 8);

    const _Float16* wdp = Wdt + (size_t)(cbase + l15) * LAT + quad * 8;
    const float* bdp = bd + cbase + quad * 4;
    float* op = out + (size_t)(rb + l15) * IN_DIM + cbase + quad * 4;

    #pragma unroll 4
    for (int ct = 0; ct < 16; ++ct) {
        half8 aw = *(const half8*)(wdp + ct * 16 * LAT);   // 16 output cols
        float4v bias = *(const float4v*)(bdp + ct * 16);
        float4v o = __builtin_amdgcn_mfma_f32_16x16x32_f16(aw, bq, bias, 0, 0, 0);
        *(float4v*)(op + ct * 16) = o;
    }
}

extern "C" void kernel_launch(void* const* d_in, const int* in_sizes, int n_in,
                              void* d_out, int out_size, void* d_ws, size_t ws_size,
                              hipStream_t stream)
{
    const float* x  = (const float*)d_in[0];
    const float* W1 = (const float*)d_in[1];
    const float* b1 = (const float*)d_in[2];
    const float* W2 = (const float*)d_in[3];
    const float* b2 = (const float*)d_in[4];
    const float* W3 = (const float*)d_in[5];
    const float* b3 = (const float*)d_in[6];
    const float* qp = (const float*)d_in[7];
    const float* Wd = (const float*)d_in[8];
    const float* bd = (const float*)d_in[9];
    float* out = (float*)d_out;

    char* ws = (char*)d_ws;
    _Float16* W1t = (_Float16*)(ws);
    _Float16* W2t = (_Float16*)(ws + WS_W2T);
    _Float16* W3t = (_Float16*)(ws + WS_W3T);
    _Float16* Wdt = (_Float16*)(ws + WS_WDT);
    float*    b3o = (float*)(ws + WS_B3O);
    _Float16* qbuf= (_Float16*)(ws + WS_Q);

    prep_kernel<<<2048, 256, 0, stream>>>(W1, W2, W3, Wd, b3, qp, W1t, W2t, W3t, Wdt, b3o);
    encoder_kernel<<<512, 256, 0, stream>>>(x, W1t, W2t, W3t, b1, b2, b3o, qbuf);
    decoder_kernel<<<4096, 256, 0, stream>>>(qbuf, Wdt, bd, out);
}

// Round 4
// 491.689 us; speedup vs baseline: 1.2093x; 1.0733x over previous
//
#include <hip/hip_runtime.h>
#include <hip/hip_bf16.h>

#define B_SZ   16384
#define IN_DIM 4096
#define H1D    128
#define H2D    64
#define LAT    32

typedef _Float16 half8 __attribute__((ext_vector_type(8)));
typedef _Float16 half4 __attribute__((ext_vector_type(4)));
typedef float float4v __attribute__((ext_vector_type(4)));

// ---- workspace layout (bytes) ----
#define WS_W2T  1048576
#define WS_W3T  1064960
#define WS_WDT  1069056
#define WS_B3O  1331200
#define WS_Q    1331328

// -------- prepass: transpose + fp32->fp16 convert weights, fold qparams into b3 --------
__global__ __launch_bounds__(256) void prep_kernel(
    const float* __restrict__ W1, const float* __restrict__ W2,
    const float* __restrict__ W3, const float* __restrict__ Wd,
    const float* __restrict__ b3, const float* __restrict__ qp,
    _Float16* __restrict__ W1t, _Float16* __restrict__ W2t,
    _Float16* __restrict__ W3t, _Float16* __restrict__ Wdt,
    float* __restrict__ b3off)
{
    int t = blockIdx.x * 256 + threadIdx.x;
    if (t < IN_DIM * H1D) {              // W1[k][n] -> W1t[n][k]
        int k = t >> 7, n = t & 127;
        W1t[n * IN_DIM + k] = (_Float16)W1[t];
    }
    if (t < LAT * IN_DIM) {              // Wd[k][n] -> Wdt[n][k]
        int k = t >> 12, n = t & 4095;
        Wdt[n * LAT + k] = (_Float16)Wd[t];
    }
    if (t < H1D * H2D) {                 // W2[k][n] -> W2t[n][k]
        int k = t >> 6, n = t & 63;
        W2t[n * H1D + k] = (_Float16)W2[t];
    }
    if (t < H2D * LAT) {                 // W3[k][n] -> W3t[n][k]
        int k = t >> 5, n = t & 31;
        W3t[n * H2D + k] = (_Float16)W3[t];
    }
    if (t < LAT) {
        float s = b3[t];
        #pragma unroll
        for (int r = 0; r < 6; ++r) s += qp[r * LAT + t];
        b3off[t] = s;
    }
}

static __device__ __forceinline__ half8 cvt8(float4v v0, float4v v1) {
    half8 h;
    h[0] = (_Float16)v0[0]; h[1] = (_Float16)v0[1];
    h[2] = (_Float16)v0[2]; h[3] = (_Float16)v0[3];
    h[4] = (_Float16)v1[0]; h[5] = (_Float16)v1[1];
    h[6] = (_Float16)v1[2]; h[7] = (_Float16)v1[3];
    return h;
}

// -------- encoder v2: double-buffered LDS x-staging, column-split waves --------
// 512 blocks x 512 threads (8 waves); block = 32 rows; wave w -> layer-1 cols
// [16w, 16w+16), full-K accumulation in regs (K-split partial buffer deleted:
// LDS 76 KB -> 26 KB). Per K-chunk(128): stage x fp32->fp16 into LDS (loads
// issued BEFORE the chunk's MFMAs, ds_write after = T14 issue-early/write-late),
// MFMA A-frags from LDS, B-frags (W1t) direct from L2. 2 blocks/CU x 8 waves
// = 16 waves/CU, 2x round-0's encoder occupancy, with structural (not TLP)
// latency hiding on the x stream.
#define XS_STRIDE 136   // fp16 row stride: granule residue (l15+quad)%8 -> bank-balanced
#define XS_SZ     (32 * XS_STRIDE)

__global__ __launch_bounds__(512, 2) void encoder_kernel(
    const float* __restrict__ x,
    const _Float16* __restrict__ W1t, const _Float16* __restrict__ W2t,
    const _Float16* __restrict__ W3t,
    const float* __restrict__ b1, const float* __restrict__ b2,
    const float* __restrict__ b3off, _Float16* __restrict__ qout)
{
    __shared__ alignas(16) _Float16 xs[2 * XS_SZ];     // 17408 B
    __shared__ alignas(16) _Float16 h1s[32 * 136];     // 8704 B
    _Float16* h2s = xs;                                // [32][72], aliases xs (dead by then)

    const int tid  = threadIdx.x;
    const int lane = tid & 63;
    const int w    = tid >> 6;        // 0..7 = layer-1 col-frag
    const int l15  = lane & 15;
    const int quad = lane >> 4;       // 0..3
    const int rb0  = blockIdx.x * 32;

    // staging geometry: 512 threads cover 32 rows x 128 cols per chunk
    const int srow = tid >> 4;        // 0..31
    const int scol = (tid & 15) * 8;  // 0..120
    const float* sx = x + (size_t)(rb0 + srow) * IN_DIM + scol;

    // ---- layer 1: acc[2 row-frags], cols w*16..+16, K-chunks of 128 ----
    float4v acc0 = (float4v){0.f, 0.f, 0.f, 0.f};
    float4v acc1 = (float4v){0.f, 0.f, 0.f, 0.f};

    const _Float16* wp = W1t + (size_t)(w * 16 + l15) * IN_DIM + quad * 8;

    // prologue: stage chunk 0
    {
        float4v r0 = *(const float4v*)(sx);
        float4v r1 = *(const float4v*)(sx + 4);
        *(half8*)(xs + srow * XS_STRIDE + scol) = cvt8(r0, r1);
    }
    __syncthreads();

    for (int c = 0; c < 32; ++c) {
        _Float16* cur = xs + (c & 1) * XS_SZ;
        _Float16* nxt = xs + ((c + 1) & 1) * XS_SZ;

        // issue next chunk's global loads early (latency hides under MFMAs)
        float4v r0, r1;
        const bool have_next = (c + 1 < 32);
        if (have_next) {
            const float* s = sx + (c + 1) * 128;
            r0 = *(const float4v*)(s);
            r1 = *(const float4v*)(s + 4);
        }

        // compute chunk c: 4 K-steps x (2 ds_read A + 1 L2 B + 2 MFMA)
        #pragma unroll
        for (int ks = 0; ks < 4; ++ks) {
            half8 a0 = *(const half8*)(cur + l15 * XS_STRIDE + ks * 32 + quad * 8);
            half8 a1 = *(const half8*)(cur + (16 + l15) * XS_STRIDE + ks * 32 + quad * 8);
            half8 b  = *(const half8*)(wp + c * 128 + ks * 32);
            acc0 = __builtin_amdgcn_mfma_f32_16x16x32_f16(a0, b, acc0, 0, 0, 0);
            acc1 = __builtin_amdgcn_mfma_f32_16x16x32_f16(a1, b, acc1, 0, 0, 0);
        }

        // write-late: commit staged chunk c+1 to the other buffer
        if (have_next)
            *(half8*)(nxt + srow * XS_STRIDE + scol) = cvt8(r0, r1);
        __syncthreads();
    }

    // epilogue: bias + relu -> h1s fp16 [32][136]; D row = mg*16+quad*4+r, col = w*16+l15
    {
        float bv1 = b1[w * 16 + l15];
        #pragma unroll
        for (int r = 0; r < 4; ++r) {
            float v0 = acc0[r] + bv1;
            float v1 = acc1[r] + bv1;
            h1s[(quad * 4 + r) * 136 + w * 16 + l15]      = (_Float16)(v0 > 0.f ? v0 : 0.f);
            h1s[(16 + quad * 4 + r) * 136 + w * 16 + l15] = (_Float16)(v1 > 0.f ? v1 : 0.f);
        }
    }
    __syncthreads();

    // ---- layer 2: h2[32][64] = relu(h1 @ W2 + b2); waves 0..3 -> cols w*16..+15 ----
    if (w < 4) {
        float bv2 = b2[w * 16 + l15];
        float4v a2[2] = {(float4v){bv2, bv2, bv2, bv2}, (float4v){bv2, bv2, bv2, bv2}};
        #pragma unroll
        for (int kk = 0; kk < 4; ++kk) {
            half8 b = *(const half8*)(W2t + (w * 16 + l15) * H1D + kk * 32 + quad * 8);
            half8 a0 = *(const half8*)(h1s + l15 * 136 + kk * 32 + quad * 8);
            half8 a1 = *(const half8*)(h1s + (16 + l15) * 136 + kk * 32 + quad * 8);
            a2[0] = __builtin_amdgcn_mfma_f32_16x16x32_f16(a0, b, a2[0], 0, 0, 0);
            a2[1] = __builtin_amdgcn_mfma_f32_16x16x32_f16(a1, b, a2[1], 0, 0, 0);
        }
        // h2s aliases xs: all xs reads finished before the last loop barrier
        #pragma unroll
        for (int mg = 0; mg < 2; ++mg)
            #pragma unroll
            for (int r = 0; r < 4; ++r) {
                float v = a2[mg][r];
                h2s[(mg * 16 + quad * 4 + r) * 72 + w * 16 + l15] = (_Float16)(v > 0.f ? v : 0.f);
            }
    }
    __syncthreads();

    // ---- layer 3 + cos: waves 0..3; wave w -> row-group w>>1, col-group w&1 ----
    if (w < 4) {
        const int mg3 = w >> 1;
        const int ct3 = w & 1;
        const int c3  = ct3 * 16 + l15;
        float bv3 = b3off[c3];
        float4v a3 = (float4v){bv3, bv3, bv3, bv3};
        #pragma unroll
        for (int kk = 0; kk < 2; ++kk) {
            half8 a = *(const half8*)(h2s + (mg3 * 16 + l15) * 72 + kk * 32 + quad * 8);
            half8 b = *(const half8*)(W3t + c3 * H2D + kk * 32 + quad * 8);
            a3 = __builtin_amdgcn_mfma_f32_16x16x32_f16(a, b, a3, 0, 0, 0);
        }
        #pragma unroll
        for (int r = 0; r < 4; ++r) {
            int row = rb0 + mg3 * 16 + quad * 4 + r;
            qout[(size_t)row * LAT + c3] = (_Float16)cosf(a3[r]);
        }
    }
}

// -------- decoder: out[16384,4096] = q @ Wd + bd --------
// Swapped-operand MFMA (A = Wd^T rows = output cols, B = q rows): D-fragment reg
// axis (quad*4+r) runs along output COLUMNS -> each lane stores 4 consecutive
// floats of one output row via global_store_dwordx4. No LDS, no barriers.
// 4096 blocks x 256 threads (16 rows x 1024 cols per block, wave w -> 256 cols).
__global__ __launch_bounds__(256, 8) void decoder_kernel(
    const _Float16* __restrict__ qin, const _Float16* __restrict__ Wdt,
    const float* __restrict__ bd, float* __restrict__ out)
{
    const int tid  = threadIdx.x;
    const int lane = tid & 63;
    const int w    = tid >> 6;        // 0..3
    const int l15  = lane & 15;
    const int quad = lane >> 4;       // 0..3
    const int stripe   = blockIdx.x >> 2;   // 0..1023 -> 16 rows each
    const int colchunk = blockIdx.x & 3;    // 0..3    -> 1024 cols each
    const int rb    = stripe * 16;
    const int cbase = colchunk * 1024 + w * 256;

    // q fragment: rows rb..rb+15, B-operand (row l15, k = quad*8..+8)
    half8 bq = *(const half8*)(qin + (size_t)(rb + l15) * LAT + quad * 8);

    const _Float16* wdp = Wdt + (size_t)(cbase + l15) * LAT + quad * 8;
    const float* bdp = bd + cbase + quad * 4;
    float* op = out + (size_t)(rb + l15) * IN_DIM + cbase + quad * 4;

    #pragma unroll 4
    for (int ct = 0; ct < 16; ++ct) {
        half8 aw = *(const half8*)(wdp + ct * 16 * LAT);   // 16 output cols
        float4v bias = *(const float4v*)(bdp + ct * 16);
        float4v o = __builtin_amdgcn_mfma_f32_16x16x32_f16(aw, bq, bias, 0, 0, 0);
        *(float4v*)(op + ct * 16) = o;
    }
}

extern "C" void kernel_launch(void* const* d_in, const int* in_sizes, int n_in,
                              void* d_out, int out_size, void* d_ws, size_t ws_size,
                              hipStream_t stream)
{
    const float* x  = (const float*)d_in[0];
    const float* W1 = (const float*)d_in[1];
    const float* b1 = (const float*)d_in[2];
    const float* W2 = (const float*)d_in[3];
    const float* b2 = (const float*)d_in[4];
    const float* W3 = (const float*)d_in[5];
    const float* b3 = (const float*)d_in[6];
    const float* qp = (const float*)d_in[7];
    const float* Wd = (const float*)d_in[8];
    const float* bd = (const float*)d_in[9];
    float* out = (float*)d_out;

    char* ws = (char*)d_ws;
    _Float16* W1t = (_Float16*)(ws);
    _Float16* W2t = (_Float16*)(ws + WS_W2T);
    _Float16* W3t = (_Float16*)(ws + WS_W3T);
    _Float16* Wdt = (_Float16*)(ws + WS_WDT);
    float*    b3o = (float*)(ws + WS_B3O);
    _Float16* qbuf= (_Float16*)(ws + WS_Q);

    prep_kernel<<<2048, 256, 0, stream>>>(W1, W2, W3, Wd, b3, qp, W1t, W2t, W3t, Wdt, b3o);
    encoder_kernel<<<512, 512, 0, stream>>>(x, W1t, W2t, W3t, b1, b2, b3o, qbuf);
    decoder_kernel<<<4096, 256, 0, stream>>>(qbuf, Wdt, bd, out);
}